// Round 3
// baseline (134.019 us; speedup 1.0000x reference)
//
#include <hip/hip_runtime.h>
#include <hip/hip_bf16.h>

#define BB 8
#define SS 4096
#define DD 1024
#define KK 32
#define EE 8
#define PP 4

// ---- output float offsets (tuple concatenated flat, in return order) ----
#define O0 0L                    // expert_weights  (B,S,E)   262144
#define O1 262144L               // expert_indices  (B,S,E)   262144
#define O2 524288L               // phi_weights     (B,S,K)  1048576
#define O3 1572864L              // soft_slots      (B,K*D)   262144
#define O4 1835008L              // expert_inputs   (B,K*D)   262144
#define O5 2097152L              // phi_logits      (B,S,K)  1048576
#define O6 3145728L              // raw_gate_probs  (B,S,K)  1048576

// ---- workspace float offsets ----
#define WA 0L        // softmax partials: 128 blocks * 64 floats
#define WB 8192L     // final m / (1/sum) per (b,k): 8*64 floats
#define WC 16384L    // K3 partials: SC * B*K*D floats

// ============ K1: logits = x @ W_phi + b; fused raw_gate/consts ============
// 512 blocks x 256 threads; each block = 64 tokens, 4 waves split D in quarters.
// W_phi accesses are wave-uniform -> compiler emits scalar (s_load) fetches.
__global__ __launch_bounds__(256) void k_logits(const float* __restrict__ x,
    const float* __restrict__ Wp, const float* __restrict__ bp,
    float* __restrict__ out)
{
    __shared__ float red[3][64][KK + 1];
    const int tid  = threadIdx.x;
    const int wv   = __builtin_amdgcn_readfirstlane(tid >> 6); // 0..3 d-quarter
    const int lane = tid & 63;
    const long g   = (long)blockIdx.x * 64 + lane;             // token = b*S+s
    const float* xrow = x + g * DD + wv * 256;
    const float* wb   = Wp + (long)wv * 256 * KK;
    float acc[KK];
#pragma unroll
    for (int k = 0; k < KK; ++k) acc[k] = 0.f;
#pragma unroll 2
    for (int dq = 0; dq < 256; dq += 4) {
        const float4 xv = *reinterpret_cast<const float4*>(xrow + dq);
        const float* wr = wb + dq * KK;
#pragma unroll
        for (int j = 0; j < 4; ++j) {
            const float xs = (j == 0) ? xv.x : (j == 1) ? xv.y : (j == 2) ? xv.z : xv.w;
#pragma unroll
            for (int k = 0; k < KK; ++k)
                acc[k] = fmaf(xs, wr[j * KK + k], acc[k]);
        }
    }
    if (wv) {
#pragma unroll
        for (int k = 0; k < KK; ++k) red[wv - 1][lane][k] = acc[k];
    }
    __syncthreads();
    if (wv == 0) {
#pragma unroll
        for (int k = 0; k < KK; ++k)
            acc[k] += red[0][lane][k] + red[1][lane][k] + red[2][lane][k] + bp[k];
        float4* pl = reinterpret_cast<float4*>(out + O5 + g * KK);
#pragma unroll
        for (int q = 0; q < 8; ++q)
            pl[q] = make_float4(acc[4*q], acc[4*q+1], acc[4*q+2], acc[4*q+3]);
        float rg[KK];
#pragma unroll
        for (int e = 0; e < EE; ++e) {
            const float m = fmaxf(fmaxf(acc[4*e], acc[4*e+1]), fmaxf(acc[4*e+2], acc[4*e+3]));
            float s = 0.f;
#pragma unroll
            for (int p = 0; p < PP; ++p) { rg[4*e+p] = __expf(acc[4*e+p] - m); s += rg[4*e+p]; }
            const float ri = 1.f / s;
#pragma unroll
            for (int p = 0; p < PP; ++p) rg[4*e+p] *= ri;
        }
        float4* prg = reinterpret_cast<float4*>(out + O6 + g * KK);
#pragma unroll
        for (int q = 0; q < 8; ++q)
            prg[q] = make_float4(rg[4*q], rg[4*q+1], rg[4*q+2], rg[4*q+3]);
        float4* pew = reinterpret_cast<float4*>(out + O0 + g * EE);
        pew[0] = make_float4(0.125f, 0.125f, 0.125f, 0.125f);
        pew[1] = make_float4(0.125f, 0.125f, 0.125f, 0.125f);
        float4* pei = reinterpret_cast<float4*>(out + O1 + g * EE);
        pei[0] = make_float4(0.f, 1.f, 2.f, 3.f);
        pei[1] = make_float4(4.f, 5.f, 6.f, 7.f);
    }
}

// ============ K2a: per-(b, s-chunk) partial max & sum(exp) over 256 rows ====
__global__ __launch_bounds__(256) void k_smpart(const float* __restrict__ out,
                                                float* __restrict__ ws)
{
    const int blk = blockIdx.x;            // b*16 + sc
    const int b = blk >> 4, sc = blk & 15;
    const int tid = threadIdx.x;
    const int wv  = __builtin_amdgcn_readfirstlane(tid >> 6);
    const long s  = (long)sc * 256 + tid;
    const float* row = out + O5 + ((long)b * SS + s) * KK;
    float v[KK];
    const float4* r4 = reinterpret_cast<const float4*>(row);
#pragma unroll
    for (int q = 0; q < 8; ++q) {
        const float4 t = r4[q];
        v[4*q] = t.x; v[4*q+1] = t.y; v[4*q+2] = t.z; v[4*q+3] = t.w;
    }
    float m[KK];
#pragma unroll
    for (int k = 0; k < KK; ++k) m[k] = v[k];
    for (int off = 1; off < 64; off <<= 1) {
#pragma unroll
        for (int k = 0; k < KK; ++k) m[k] = fmaxf(m[k], __shfl_xor(m[k], off));
    }
    __shared__ float lm[4][KK];
    __shared__ float lsum[4][KK];
    if ((tid & 63) == 0) {
#pragma unroll
        for (int k = 0; k < KK; ++k) lm[wv][k] = m[k];
    }
    __syncthreads();
#pragma unroll
    for (int k = 0; k < KK; ++k)
        m[k] = fmaxf(fmaxf(lm[0][k], lm[1][k]), fmaxf(lm[2][k], lm[3][k]));
    float sv[KK];
#pragma unroll
    for (int k = 0; k < KK; ++k) sv[k] = __expf(v[k] - m[k]);
    for (int off = 1; off < 64; off <<= 1) {
#pragma unroll
        for (int k = 0; k < KK; ++k) sv[k] += __shfl_xor(sv[k], off);
    }
    if ((tid & 63) == 0) {
#pragma unroll
        for (int k = 0; k < KK; ++k) lsum[wv][k] = sv[k];
    }
    __syncthreads();
    if (tid == 0) {
#pragma unroll
        for (int k = 0; k < KK; ++k) {
            ws[WA + (long)blk * 64 + k]      = m[k];
            ws[WA + (long)blk * 64 + 32 + k] = lsum[0][k] + lsum[1][k] + lsum[2][k] + lsum[3][k];
        }
    }
}

// ============ K2b: combine 16 chunk stats -> final m, 1/sum per (b,k) ======
__global__ __launch_bounds__(256) void k_smcomb(float* __restrict__ ws)
{
    const int tid = threadIdx.x;           // = b*32 + k  (exactly 256)
    const int b = tid >> 5, k = tid & 31;
    float m = -1e30f, s = 0.f;
    for (int c = 0; c < 16; ++c) {
        const float mc = ws[WA + (long)(b * 16 + c) * 64 + k];
        const float sc = ws[WA + (long)(b * 16 + c) * 64 + 32 + k];
        const float nm = fmaxf(m, mc);
        s = s * __expf(m - nm) + sc * __expf(mc - nm);
        m = nm;
    }
    ws[WB + (long)b * 64 + k]      = m;
    ws[WB + (long)b * 64 + 32 + k] = 1.f / s;
}

// ============ K2c: phi_weights = exp(logit - m) * rinv (elementwise) =======
__global__ __launch_bounds__(256) void k_pw(float* __restrict__ out,
                                            const float* __restrict__ ws)
{
    const long i4 = (long)blockIdx.x * 256 + threadIdx.x;   // < 262144
    const float4 l4 = reinterpret_cast<const float4*>(out + O5)[i4];
    const long idx = i4 * 4;
    const int b  = (int)(idx >> 17);       // / (S*K = 131072)
    const int k0 = (int)(idx & 31);
    const float* mb = ws + WB + (long)b * 64;
    const float lv[4] = {l4.x, l4.y, l4.z, l4.w};
    float r[4];
#pragma unroll
    for (int j = 0; j < 4; ++j) {
        const int k = k0 + j;
        r[j] = __expf(lv[j] - mb[k]) * mb[32 + k];
    }
    reinterpret_cast<float4*>(out + O2)[i4] = make_float4(r[0], r[1], r[2], r[3]);
}

// ============ K3: partial soft_slots[b][k][d] = sum_s pw * x ===============
// blocks = B * 4(dchunk) * SC(s-chunk); thread owns one d column, acc[32].
// phi_weights row loads are wave-uniform -> scalar loads.
// direct path: SC==1 partials go straight to out+O3 (workspace too small).
__global__ __launch_bounds__(256) void k_slots(const float* __restrict__ x,
    const float* __restrict__ out, float* __restrict__ dst, int SC, int SLEN)
{
    const int blk = blockIdx.x;
    const int sc  = blk % SC;
    const int t2  = blk / SC;
    const int dc  = t2 & 3;
    const int b   = t2 >> 2;
    const int d   = dc * 256 + threadIdx.x;
    float acc[KK];
#pragma unroll
    for (int k = 0; k < KK; ++k) acc[k] = 0.f;
    const long s0 = (long)sc * SLEN;
    const float* pw = out + O2 + ((long)b * SS + s0) * KK;
    const float* xp = x + ((long)b * SS + s0) * DD + d;
#pragma unroll 4
    for (int i = 0; i < SLEN; ++i) {
        const float xv = xp[(long)i * DD];
        const float* wr = pw + (long)i * KK;
#pragma unroll
        for (int k = 0; k < KK; ++k) acc[k] = fmaf(wr[k], xv, acc[k]);
    }
    float* o = dst + ((long)(sc * BB + b) * KK) * DD + d;
#pragma unroll
    for (int k = 0; k < KK; ++k) o[(long)k * DD] = acc[k];
}

// ============ K4: reduce SC partials -> soft_slots + expert_inputs =========
__global__ __launch_bounds__(256) void k_red(const float* __restrict__ src,
                                             float* __restrict__ out, int SC)
{
    const long i4 = (long)blockIdx.x * 256 + threadIdx.x;   // < 65536
    float4 s = make_float4(0.f, 0.f, 0.f, 0.f);
    const float4* p = reinterpret_cast<const float4*>(src);
    for (int c = 0; c < SC; ++c) {
        const float4 t = p[(long)c * 65536 + i4];
        s.x += t.x; s.y += t.y; s.z += t.z; s.w += t.w;
    }
    reinterpret_cast<float4*>(out + O3)[i4] = s;
    reinterpret_cast<float4*>(out + O4)[i4] = s;
}

extern "C" void kernel_launch(void* const* d_in, const int* in_sizes, int n_in,
                              void* d_out, int out_size, void* d_ws, size_t ws_size,
                              hipStream_t stream)
{
    const float* x  = (const float*)d_in[0];
    const float* Wp = (const float*)d_in[1];
    const float* bp = (const float*)d_in[2];
    float* out = (float*)d_out;
    float* ws  = (float*)d_ws;

    const size_t wfloats = ws_size / 4;
    int SC = 0;                              // 0 => direct-to-out fallback
    if      (wfloats >= (size_t)(WC + 16L * 262144)) SC = 16;
    else if (wfloats >= (size_t)(WC +  8L * 262144)) SC = 8;
    else if (wfloats >= (size_t)(WC +  4L * 262144)) SC = 4;
    else if (wfloats >= (size_t)(WC +  2L * 262144)) SC = 2;
    else if (wfloats >= (size_t)(WC +  1L * 262144)) SC = 1;

    hipLaunchKernelGGL(k_logits, dim3(512),  dim3(256), 0, stream, x, Wp, bp, out);
    hipLaunchKernelGGL(k_smpart, dim3(128),  dim3(256), 0, stream, out, ws);
    hipLaunchKernelGGL(k_smcomb, dim3(1),    dim3(256), 0, stream, ws);
    hipLaunchKernelGGL(k_pw,     dim3(1024), dim3(256), 0, stream, out, ws);
    if (SC >= 1) {
        hipLaunchKernelGGL(k_slots, dim3(BB * 4 * SC), dim3(256), 0, stream,
                           x, out, ws + WC, SC, SS / SC);
        hipLaunchKernelGGL(k_red,   dim3(256), dim3(256), 0, stream, ws + WC, out, SC);
    } else {
        // workspace too small for partials: single-chunk directly into out+O3,
        // then duplicate O3 -> O4.
        hipLaunchKernelGGL(k_slots, dim3(BB * 4), dim3(256), 0, stream,
                           x, out, out + O3, 1, SS);
        hipLaunchKernelGGL(k_red,   dim3(256), dim3(256), 0, stream, out + O3, out, 1);
    }
}